// Round 5
// baseline (385.600 us; speedup 1.0000x reference)
//
#include <hip/hip_runtime.h>

#define B_TOTAL 32768
#define NF 200
#define D_IN 5
#define NH 15
#define NOUT 30

typedef _Float16 half8 __attribute__((ext_vector_type(8)));
typedef _Float16 half4_t __attribute__((ext_vector_type(4)));
typedef float f32x4 __attribute__((ext_vector_type(4)));
typedef float f32x2 __attribute__((ext_vector_type(2)));

// ws layout: Bc fp16 [f 200][half 2][n 16][k8]  (= 256 halfs/f, 102400 B)
//            w3T fp32 [part 10][w 4][n 16][slot 12] (7680 floats) at +102400 B
// Bc k8 per (f, o=half*16+n): {Wc[0..4][o], bc[o], 0, 0}; o>=30 rows written as
// zero by precompute. w3T slots 10,11 per group are never read.
#define WS_BC_BYTES 102400

#define GPF 8   // features per precompute block; 200/8 = 25 blocks

// LDS-staged precompute: coalesced float4 loads of all per-f weights, then each
// of the 256 threads computes one (f, o) folded column from LDS.
__global__ __launch_bounds__(256) void precompute_kernel(
    const float* __restrict__ W1, const float* __restrict__ b1,
    const float* __restrict__ W2, const float* __restrict__ b2,
    const float* __restrict__ W3, _Float16* __restrict__ Bc,
    float* __restrict__ w3T)
{
    __shared__ __align__(16) float sW1[GPF * 75];    // [fi][i*15+h]
    __shared__ __align__(16) float sW2[GPF * 450];   // [fi][h*30+o]
    __shared__ __align__(16) float sb1[GPF * 15];
    __shared__ __align__(16) float sb2[GPF * 30];
    __shared__ __align__(16) float sW3[GPF * 30];

    const int tid = threadIdx.x;
    const int f0  = blockIdx.x * GPF;

    // stage weights: every block slice is 16B-aligned (f0 multiple of 8)
    {
        const f32x4* g1 = (const f32x4*)(W1 + (size_t)f0 * 75);   // 150 f4
        if (tid < 150) ((f32x4*)sW1)[tid] = g1[tid];
        const f32x4* g2 = (const f32x4*)(W2 + (size_t)f0 * 450);  // 900 f4
        for (int j = tid; j < 900; j += 256) ((f32x4*)sW2)[j] = g2[j];
        if (tid < 30)
            ((f32x4*)sb1)[tid] = ((const f32x4*)(b1 + (size_t)f0 * 15))[tid];
        if (tid >= 32 && tid < 92)
            ((f32x4*)sb2)[tid - 32] = ((const f32x4*)(b2 + (size_t)f0 * 30))[tid - 32];
        if (tid >= 96 && tid < 156)
            ((f32x4*)sW3)[tid - 96] = ((const f32x4*)(W3 + (size_t)f0 * 30))[tid - 96];
    }
    __syncthreads();

    const int fi = tid >> 5;       // local f
    const int r  = tid & 31;       // Bc row within f
    const int hf = r >> 4;
    const int n  = r & 15;
    const int o  = hf * 16 + n;
    const int f  = f0 + fi;

    half8 row = {};                // o >= 30 rows stay all-zero
    if (o < NOUT) {
        float bcv = sb2[fi * 30 + o];
        float wc0 = 0.f, wc1 = 0.f, wc2 = 0.f, wc3 = 0.f, wc4 = 0.f;
        #pragma unroll
        for (int h = 0; h < NH; ++h) {
            const float w2v = sW2[fi * 450 + h * 30 + o];
            bcv = fmaf(sb1[fi * 15 + h], w2v, bcv);
            wc0 = fmaf(sW1[fi * 75 +  0 + h], w2v, wc0);
            wc1 = fmaf(sW1[fi * 75 + 15 + h], w2v, wc1);
            wc2 = fmaf(sW1[fi * 75 + 30 + h], w2v, wc2);
            wc3 = fmaf(sW1[fi * 75 + 45 + h], w2v, wc3);
            wc4 = fmaf(sW1[fi * 75 + 60 + h], w2v, wc4);
        }
        row[0] = (_Float16)wc0; row[1] = (_Float16)wc1; row[2] = (_Float16)wc2;
        row[3] = (_Float16)wc3; row[4] = (_Float16)wc4;
        row[5] = (_Float16)bcv; // pairs with the 1.0 bias slot in A
        row[6] = (_Float16)0.f; row[7] = (_Float16)0.f;

        const int p = f / 20, fl = f % 20, Kg = fl / 4, w = fl % 4;
        w3T[((size_t)(p * 4 + w) * 16 + n) * 12 + (Kg * 2 + hf)] = sW3[fi * 30 + o];
    }
    *(half8*)(Bc + (size_t)f * 256 + r * 8) = row;   // coalesced b128 store
}

// ---------------- Main kernel ----------------
// Grid 2048 blocks x 256 thr (4 waves); block owns 16 b-rows, loops all 10
// f-parts with acc persistent in VGPRs; epilogue once, plain store, no
// atomics. Prefetch state lives in NAMED ext-vector registers (f32x4 +
// scalar) -- no local arrays, so no scratch (R4's 89 MB WRITE_SIZE bug).
// 18.7 KB LDS + launch_bounds(256,8) -> 8 blocks/CU (32 waves/CU) so TLP
// hides HBM latency across the per-part barriers.
// MFMA mfma_f32_16x16x16_f16: quads 0,1 real k8, quads 2,3 zero-B (A mirrors
// q&1). Bias via the 1.0 A-column. Epilogue: LDS-transpose reduction over the
// 16 n-lanes + cross-wave combine, plain store of out (+b3).
#define FPART 20
#define NPARTS 10
#define BTILE 16

__global__ __launch_bounds__(256, 8) void mlp_kernel(
    const float* __restrict__ y, const _Float16* __restrict__ Bc,
    const float* __restrict__ w3T, const float* __restrict__ b3,
    float* __restrict__ out)
{
    __shared__ __align__(16) _Float16 sy[BTILE * 168]; // [b][fl 20 x8 + pad8]
    __shared__ __align__(16) _Float16 sB[20 * 256];    // part's Bc, linear
    __shared__ __align__(16) float    sw3[768];        // part's w3T
    __shared__ __align__(16) _Float16 szero[8];

    const int tid = threadIdx.x;
    const int b0  = blockIdx.x * BTILE;

    if (tid < 8) szero[tid] = (_Float16)0.f;

    // y staging task map: 320 tasks (b 16 x fl 20) = tid, and tid+256 (tid<64)
    const int bt0 = tid / 20,            flt0 = tid - bt0 * 20;
    const int id1 = tid + 256; const int bt1 = id1 / 20, flt1 = id1 - bt1 * 20;
    const bool has1 = (tid < 64);
    const bool has2 = (tid < 128);   // sB third chunk
    const bool hasw = (tid < 192);   // sw3

    const float* ybase = y + (size_t)b0 * (NF * D_IN);
    const float* ysrc0 = ybase + (size_t)bt0 * (NF * D_IN) + flt0 * 5;
    const float* ysrc1 = ybase + (size_t)bt1 * (NF * D_IN) + flt1 * 5;

    // prefetch registers (all named vectors/scalars -> VGPR-resident)
    f32x4 y0a, y1a, vB0, vB1, vB2, vw;
    float y0b, y1b;

    // ---- prologue: prefetch part 0 ----
    {
        __builtin_memcpy(&y0a, ysrc0, 16); y0b = ysrc0[4];
        if (has1) { __builtin_memcpy(&y1a, ysrc1, 16); y1b = ysrc1[4]; }
        const f32x4* g = (const f32x4*)Bc;
        vB0 = g[tid]; vB1 = g[tid + 256];
        if (has2) vB2 = g[tid + 512];
        if (hasw) vw = ((const f32x4*)w3T)[tid];
    }

    const int lane = tid & 63;
    const int w    = tid >> 6;       // wave id == f_in_group
    const int n    = lane & 15;      // A row m / B col n / C col
    const int q    = lane >> 4;      // quad == k-block
    const int par  = q & 1;

    float acc[4];
    #pragma unroll
    for (int g = 0; g < 4; ++g) acc[g] = 0.f;
    const f32x4 z4 = {0.f, 0.f, 0.f, 0.f};

    #pragma unroll 1
    for (int p = 0; p < NPARTS; ++p) {
        __syncthreads();             // previous part's compute done; LDS free
        // ---- write staged registers to LDS ----
        {
            half8 h;
            h[0]=(_Float16)y0a[0]; h[1]=(_Float16)y0a[1]; h[2]=(_Float16)y0a[2];
            h[3]=(_Float16)y0a[3]; h[4]=(_Float16)y0b;
            h[5]=(_Float16)1.0f;   h[6]=(_Float16)0.f;   h[7]=(_Float16)0.f;
            *(half8*)&sy[bt0 * 168 + flt0 * 8] = h;
            if (has1) {
                h[0]=(_Float16)y1a[0]; h[1]=(_Float16)y1a[1]; h[2]=(_Float16)y1a[2];
                h[3]=(_Float16)y1a[3]; h[4]=(_Float16)y1b;
                h[5]=(_Float16)1.0f;
                *(half8*)&sy[bt1 * 168 + flt1 * 8] = h;
            }
            f32x4* s = (f32x4*)sB;
            s[tid] = vB0; s[tid + 256] = vB1;
            if (has2) s[tid + 512] = vB2;
            if (hasw) ((f32x4*)sw3)[tid] = vw;
        }
        __syncthreads();
        // ---- issue prefetch for part p+1 (lands under this part's compute
        //      and under other resident blocks' compute) ----
        if (p + 1 < NPARTS) {
            const int df = (p + 1) * FPART * D_IN;   // float offset within row
            __builtin_memcpy(&y0a, ysrc0 + df, 16); y0b = ysrc0[df + 4];
            if (has1) { __builtin_memcpy(&y1a, ysrc1 + df, 16); y1b = ysrc1[df + 4]; }
            const f32x4* g = (const f32x4*)(Bc + (size_t)(p + 1) * FPART * 256);
            vB0 = g[tid]; vB1 = g[tid + 256];
            if (has2) vB2 = g[tid + 512];
            if (hasw) vw = ((const f32x4*)w3T)[(size_t)(p + 1) * 192 + tid];
        }
        // ---- compute this part: 5 Kg x 2 MFMA ----
        #pragma unroll
        for (int Kg = 0; Kg < 5; ++Kg) {
            const int fl = Kg * 4 + w;   // this wave's f_local
            const half4_t A0 = *(const half4_t*)&sy[n * 168 + fl * 8 + par * 4];
            const _Float16* bq0 = (q < 2) ? &sB[fl * 256 + n * 8 + par * 4]        : szero;
            const _Float16* bq1 = (q < 2) ? &sB[fl * 256 + (16 + n) * 8 + par * 4] : szero;
            const half4_t Bf0 = *(const half4_t*)bq0;
            const half4_t Bf1 = *(const half4_t*)bq1;
            const f32x2 w3p = *(const f32x2*)&sw3[(w * 16 + n) * 12 + Kg * 2];

            f32x4 c;
            c = __builtin_amdgcn_mfma_f32_16x16x16f16(A0, Bf0, z4, 0, 0, 0);
            #pragma unroll
            for (int g = 0; g < 4; ++g) acc[g] += fmaxf(c[g], 0.f) * w3p[0];
            c = __builtin_amdgcn_mfma_f32_16x16x16f16(A0, Bf1, z4, 0, 0, 0);
            #pragma unroll
            for (int g = 0; g < 4; ++g) acc[g] += fmaxf(c[g], 0.f) * w3p[1];
        }
    }

    // ---- epilogue (once): LDS-transpose reduction over the 16 n-lanes ----
    __syncthreads();                  // all waves done reading sy/sB
    float* sacc = (float*)sy;         // [w][row 16][stride 20 dw] = 5120 B
    {
        float* base = sacc + w * (16 * 20);
        #pragma unroll
        for (int g = 0; g < 4; ++g)
            base[(q * 4 + g) * 20 + n] = acc[g];      // 2-way max aliasing
    }
    float v = 0.f;
    if (lane < 16) {                  // per-wave row sums (in-wave DS ordering)
        const float* srow = sacc + w * (16 * 20) + lane * 20;
        const f32x4 r0 = *(const f32x4*)(srow);
        const f32x4 r1 = *(const f32x4*)(srow + 4);
        const f32x4 r2 = *(const f32x4*)(srow + 8);
        const f32x4 r3 = *(const f32x4*)(srow + 12);
        v = ((r0[0] + r0[1]) + (r0[2] + r0[3]))
          + ((r1[0] + r1[1]) + (r1[2] + r1[3]))
          + ((r2[0] + r2[1]) + (r2[2] + r2[3]))
          + ((r3[0] + r3[1]) + (r3[2] + r3[3]));
    }
    float* sp = (float*)sB;           // [w][16] scratch (sB dead)
    if (lane < 16) sp[w * 16 + lane] = v;
    __syncthreads();
    if (tid < 16) {
        const float s = (sp[tid] + sp[16 + tid]) + (sp[32 + tid] + sp[48 + tid]) + b3[0];
        out[b0 + tid] = s;            // plain coalesced store, written once
    }
}

extern "C" void kernel_launch(void* const* d_in, const int* in_sizes, int n_in,
                              void* d_out, int out_size, void* d_ws, size_t ws_size,
                              hipStream_t stream) {
    const float* y  = (const float*)d_in[0];
    const float* W1 = (const float*)d_in[1];
    const float* b1 = (const float*)d_in[2];
    const float* W2 = (const float*)d_in[3];
    const float* b2 = (const float*)d_in[4];
    const float* W3 = (const float*)d_in[5];
    const float* b3 = (const float*)d_in[6];
    float* out = (float*)d_out;

    _Float16* Bc  = (_Float16*)d_ws;
    float*    w3T = (float*)((char*)d_ws + WS_BC_BYTES);

    // no memsets: mlp writes every out element exactly once (plain store);
    // precompute writes every Bc byte (pad rows included).
    precompute_kernel<<<NF / GPF, 256, 0, stream>>>(W1, b1, W2, b2, W3, Bc, w3T);
    mlp_kernel<<<B_TOTAL / BTILE, 256, 0, stream>>>(y, Bc, w3T, b3, out);
}

// Round 6
// 207.913 us; speedup vs baseline: 1.8546x; 1.8546x over previous
//
#include <hip/hip_runtime.h>

#define B_TOTAL 32768
#define NF 200
#define D_IN 5
#define NH 15
#define NOUT 30

typedef _Float16 half8 __attribute__((ext_vector_type(8)));
typedef _Float16 half4_t __attribute__((ext_vector_type(4)));
typedef float f32x4 __attribute__((ext_vector_type(4)));
typedef float f32x2 __attribute__((ext_vector_type(2)));

// ws layout: Bc fp16 [f 200][half 2][n 16][k8]  (= 256 halfs/f, 102400 B)
//            w3T fp32 [part 10][w 4][n 16][slot 12] (7680 floats) at +102400 B
// Bc k8 per (f, o=half*16+n): {Wc[0..4][o], bc[o], 0, 0}; o>=30 rows written as
// zero by precompute (no ws memset needed). w3T slots 10,11 per group are never
// read (only Kg*2+hf, Kg<5), so poison there is harmless (staged but unused).
#define WS_BC_BYTES 102400
#define WS_TOTAL (102400 + 30720)

#define GPF 8   // features per precompute block; 200/8 = 25 blocks

// LDS-staged precompute: coalesced float4 loads of all per-f weights, then each
// of the 256 threads computes one (f, o) folded column from LDS. Also zeroes
// the output accumulator (grid-stride), replacing both hipMemsetAsync calls.
__global__ __launch_bounds__(256) void precompute_kernel(
    const float* __restrict__ W1, const float* __restrict__ b1,
    const float* __restrict__ W2, const float* __restrict__ b2,
    const float* __restrict__ W3, _Float16* __restrict__ Bc,
    float* __restrict__ w3T, float* __restrict__ out)
{
    __shared__ __align__(16) float sW1[GPF * 75];    // [fi][i*15+h]
    __shared__ __align__(16) float sW2[GPF * 450];   // [fi][h*30+o]
    __shared__ __align__(16) float sb1[GPF * 15];
    __shared__ __align__(16) float sb2[GPF * 30];
    __shared__ __align__(16) float sW3[GPF * 30];

    const int tid = threadIdx.x;
    const int f0  = blockIdx.x * GPF;

    // zero the output accumulator: 8192 float4 over 6400 threads (grid-stride)
    {
        const f32x4 z4 = {0.f, 0.f, 0.f, 0.f};
        for (int j = blockIdx.x * 256 + tid; j < B_TOTAL / 4; j += 25 * 256)
            ((f32x4*)out)[j] = z4;
    }

    // stage weights: every block slice is 16B-aligned (f0 multiple of 8)
    {
        const f32x4* g1 = (const f32x4*)(W1 + (size_t)f0 * 75);   // 150 f4
        if (tid < 150) ((f32x4*)sW1)[tid] = g1[tid];
        const f32x4* g2 = (const f32x4*)(W2 + (size_t)f0 * 450);  // 900 f4
        for (int j = tid; j < 900; j += 256) ((f32x4*)sW2)[j] = g2[j];
        if (tid < 30)
            ((f32x4*)sb1)[tid] = ((const f32x4*)(b1 + (size_t)f0 * 15))[tid];
        if (tid >= 32 && tid < 92)
            ((f32x4*)sb2)[tid - 32] = ((const f32x4*)(b2 + (size_t)f0 * 30))[tid - 32];
        if (tid >= 96 && tid < 156)
            ((f32x4*)sW3)[tid - 96] = ((const f32x4*)(W3 + (size_t)f0 * 30))[tid - 96];
    }
    __syncthreads();

    const int fi = tid >> 5;       // local f
    const int r  = tid & 31;       // Bc row within f
    const int hf = r >> 4;
    const int n  = r & 15;
    const int o  = hf * 16 + n;
    const int f  = f0 + fi;

    half8 row = {};                // o >= 30 rows stay all-zero
    if (o < NOUT) {
        float bcv = sb2[fi * 30 + o];
        float wc0 = 0.f, wc1 = 0.f, wc2 = 0.f, wc3 = 0.f, wc4 = 0.f;
        #pragma unroll
        for (int h = 0; h < NH; ++h) {
            const float w2v = sW2[fi * 450 + h * 30 + o];
            bcv = fmaf(sb1[fi * 15 + h], w2v, bcv);
            wc0 = fmaf(sW1[fi * 75 +  0 + h], w2v, wc0);
            wc1 = fmaf(sW1[fi * 75 + 15 + h], w2v, wc1);
            wc2 = fmaf(sW1[fi * 75 + 30 + h], w2v, wc2);
            wc3 = fmaf(sW1[fi * 75 + 45 + h], w2v, wc3);
            wc4 = fmaf(sW1[fi * 75 + 60 + h], w2v, wc4);
        }
        row[0] = (_Float16)wc0; row[1] = (_Float16)wc1; row[2] = (_Float16)wc2;
        row[3] = (_Float16)wc3; row[4] = (_Float16)wc4;
        row[5] = (_Float16)bcv; // pairs with the 1.0 bias slot in A
        row[6] = (_Float16)0.f; row[7] = (_Float16)0.f;

        const int p = f / 20, fl = f % 20, Kg = fl / 4, w = fl % 4;
        w3T[((size_t)(p * 4 + w) * 16 + n) * 12 + (Kg * 2 + hf)] = sW3[fi * 30 + o];
    }
    *(half8*)(Bc + (size_t)f * 256 + r * 8) = row;   // coalesced b128 store
}

// ---------------- Main kernel ----------------
// Block 256 thr (4 waves) = 64 b (4 M-tiles) x 20 f (5 K-groups of 4 f).
// Wave w handles f_local == w (mod 4). Per Kg: one f per MFMA now, using
// mfma_f32_16x16x16_f16 (K=16): quads 0,1 carry the real k8 (b64 reads,
// half the LDS bytes of the old b128/x32 scheme); quads 2,3 get zero-B
// (A mirrors q&1 there, so 0 x finite = 0). Bias via the 1.0 A-column.
// Epilogue: relu*w3 into acc, then LDS-transpose reduction (scratch aliased
// onto sy, dead after barrier) + block-level combine -> 64 atomics/block.
#define FPART 20
#define NPARTS 10

__global__ __launch_bounds__(256, 4) void mlp_kernel(
    const float* __restrict__ y, const _Float16* __restrict__ Bc,
    const float* __restrict__ w3T, const float* __restrict__ b3,
    float* __restrict__ out)
{
    __shared__ __align__(16) _Float16 sy[64 * 168];   // [b][f-slot 20 x8 + pad8]
    __shared__ __align__(16) _Float16 sB[20 * 256];   // part's Bc, linear
    __shared__ __align__(16) float    sw3[4 * 16 * 12];
    __shared__ __align__(16) _Float16 szero[8];

    const int tid = threadIdx.x;
    const int b0  = blockIdx.x * 64;
    const int p   = blockIdx.y;
    const int f0  = p * FPART;

    if (tid < 8) szero[tid] = (_Float16)0.f;
    // stage B: 20*256 halfs = 640 float4
    {
        const f32x4* g = (const f32x4*)(Bc + (size_t)f0 * 256);
        f32x4* s = (f32x4*)sB;
        s[tid]       = g[tid];
        s[tid + 256] = g[tid + 256];
        if (tid < 128) s[tid + 512] = g[tid + 512];
    }
    // stage w3T: 768 floats = 192 float4
    if (tid < 192) ((f32x4*)sw3)[tid] = ((const f32x4*)w3T)[(size_t)p * 192 + tid];
    // stage y: 1280 (b,f) tasks; vectorized loads, single b128 LDS write/task
    #pragma unroll
    for (int it = 0; it < 5; ++it) {
        const int id = tid + it * 256;
        const int b  = id / 20;
        const int fl = id - b * 20;
        const float* src = y + (size_t)(b0 + b) * (NF * D_IN) + (size_t)(f0 + fl) * 5;
        float v[5];
        __builtin_memcpy(v, src, 20);   // dwordx4 + dword (align 4)
        half8 h;
        h[0] = (_Float16)v[0]; h[1] = (_Float16)v[1]; h[2] = (_Float16)v[2];
        h[3] = (_Float16)v[3]; h[4] = (_Float16)v[4];
        h[5] = (_Float16)1.0f; h[6] = (_Float16)0.f; h[7] = (_Float16)0.f;
        *(half8*)&sy[b * 168 + fl * 8] = h;   // byte off = b*336 + fl*16, 16B-aligned
    }
    __syncthreads();

    const int lane = tid & 63;
    const int w    = tid >> 6;       // wave id == f_in_group
    const int n    = lane & 15;      // A row m / B col n / C col
    const int q    = lane >> 4;      // quad == k-block (k = q*4 + i for x16)

    float acc[4][4];
    #pragma unroll
    for (int Mt = 0; Mt < 4; ++Mt)
        #pragma unroll
        for (int g = 0; g < 4; ++g) acc[Mt][g] = 0.f;
    const f32x4 z4 = {0.f, 0.f, 0.f, 0.f};

    #pragma unroll 1
    for (int Kg = 0; Kg < 5; ++Kg) {
        const int fl = Kg * 4 + w;   // this wave's f_local
        // A frag (b64): quad q holds k=4q..4q+3 of the f-slot; quads 2,3 are
        // dead (B=0 there) but must be finite -> mirror q&1.
        half4_t A[4];
        #pragma unroll
        for (int Mt = 0; Mt < 4; ++Mt)
            A[Mt] = *(const half4_t*)&sy[(Mt * 16 + n) * 168 + fl * 8 + (q & 1) * 4];

        const _Float16* bq0 = (q < 2) ? &sB[fl * 256 + n * 8 + (q & 1) * 4]        : szero;
        const _Float16* bq1 = (q < 2) ? &sB[fl * 256 + (16 + n) * 8 + (q & 1) * 4] : szero;
        const half4_t Bf0 = *(const half4_t*)bq0;
        const half4_t Bf1 = *(const half4_t*)bq1;

        const f32x2 w3p = *(const f32x2*)&sw3[(w * 16 + n) * 12 + Kg * 2];
        const float w30 = w3p[0], w31 = w3p[1];

        #pragma unroll
        for (int Mt = 0; Mt < 4; ++Mt) {
            f32x4 c0 = __builtin_amdgcn_mfma_f32_16x16x16f16(A[Mt], Bf0, z4, 0, 0, 0);
            f32x4 c1 = __builtin_amdgcn_mfma_f32_16x16x16f16(A[Mt], Bf1, z4, 0, 0, 0);
            #pragma unroll
            for (int g = 0; g < 4; ++g)
                acc[Mt][g] += fmaxf(c0[g], 0.f) * w30 + fmaxf(c1[g], 0.f) * w31;
        }
    }

    // ---- epilogue: LDS-transpose reduction over the 16 n-lanes ----
    __syncthreads();                  // all waves done reading sy/sB
    float* sacc = (float*)sy;         // [w][row 64][stride 20 dw], 20480 B < sy
    {
        float* base = sacc + w * (64 * 20);
        #pragma unroll
        for (int Mt = 0; Mt < 4; ++Mt)
            #pragma unroll
            for (int g = 0; g < 4; ++g)
                base[(Mt * 16 + q * 4 + g) * 20 + n] = acc[Mt][g];  // 2-way max
    }
    // each lane sums its own wave's row b=lane (written above by this wave)
    const float* srow = sacc + w * (64 * 20) + lane * 20;
    f32x4 r0 = *(const f32x4*)(srow);
    f32x4 r1 = *(const f32x4*)(srow + 4);
    f32x4 r2 = *(const f32x4*)(srow + 8);
    f32x4 r3 = *(const f32x4*)(srow + 12);
    float v = ((r0[0] + r0[1]) + (r0[2] + r0[3]))
            + ((r1[0] + r1[1]) + (r1[2] + r1[3]))
            + ((r2[0] + r2[1]) + (r2[2] + r2[3]))
            + ((r3[0] + r3[1]) + (r3[2] + r3[3]));
    // cross-wave combine in sB scratch (sB dead after barrier above)
    float* sp = (float*)sB;           // [w][64]
    sp[w * 64 + lane] = v;
    __syncthreads();
    if (tid < 64) {
        float s = (sp[tid] + sp[64 + tid]) + (sp[128 + tid] + sp[192 + tid]);
        if (p == 0) s += b3[0];
        atomicAdd(&out[b0 + tid], s);
    }
}

extern "C" void kernel_launch(void* const* d_in, const int* in_sizes, int n_in,
                              void* d_out, int out_size, void* d_ws, size_t ws_size,
                              hipStream_t stream) {
    const float* y  = (const float*)d_in[0];
    const float* W1 = (const float*)d_in[1];
    const float* b1 = (const float*)d_in[2];
    const float* W2 = (const float*)d_in[3];
    const float* b2 = (const float*)d_in[4];
    const float* W3 = (const float*)d_in[5];
    const float* b3 = (const float*)d_in[6];
    float* out = (float*)d_out;

    _Float16* Bc  = (_Float16*)d_ws;
    float*    w3T = (float*)((char*)d_ws + WS_BC_BYTES);

    // no memsets: precompute zeroes `out` and writes every Bc byte (pad rows
    // included); unwritten w3T slots are never read by mlp_kernel.
    precompute_kernel<<<NF / GPF, 256, 0, stream>>>(W1, b1, W2, b2, W3, Bc, w3T, out);
    mlp_kernel<<<dim3(B_TOTAL / 64, NPARTS), 256, 0, stream>>>(y, Bc, w3T, b3, out);
}